// Round 7
// baseline (304.639 us; speedup 1.0000x reference)
//
#include <hip/hip_runtime.h>
#include <stdint.h>
#include <stddef.h>

typedef __attribute__((ext_vector_type(4))) float f32x4;
typedef __attribute__((ext_vector_type(8))) short bf16x8;

#define BMN 256      // block tile M = N
#define BK  64       // K per K-tile
#define NTHREADS 512

// Round-to-nearest-even fp32 mantissa to 10 bits (shift = 23-10 = 13).
__device__ __forceinline__ float round_m10(float x) {
    int b = __float_as_int(x);
    int rb = ((b >> 13) & 1) + 0x0FFF;
    b = (b + rb) & (int)0xFFFFE000;
    return __int_as_float(b);
}

__device__ __forceinline__ unsigned short f32_to_bf16(float x) {
    unsigned int u = __float_as_uint(x);
    u += 0x7FFFu + ((u >> 16) & 1u);
    return (unsigned short)(u >> 16);
}

// fp32 -> bf16 with the 3-bit bank swizzle BAKED IN: the 16B chunk at logical
// (row, c) is stored at (row, (c & ~7) | ((c&7) ^ (row&7))). Permutation acts
// within each 128B row-window; all tile offsets are 128B-aligned, so LDS
// staging reads LINEARLY and inherits the swizzle (rule #21).
// FUSED single launch for both tensors (x then w) — verified R19.
__global__ void convert2_f32_bf16_swz(const float* __restrict__ inx,
                                      unsigned short* __restrict__ outx,
                                      const float* __restrict__ inw,
                                      unsigned short* __restrict__ outw,
                                      long nx8, long ntot, int cpr) {
    long g = (long)blockIdx.x * blockDim.x + threadIdx.x;
    const long stride = (long)gridDim.x * blockDim.x;
    for (; g < ntot; g += stride) {
        const float* in;
        unsigned short* out;
        long gg;
        if (g < nx8) { in = inx; out = outx; gg = g; }
        else         { in = inw; out = outw; gg = g - nx8; }
        const long row = gg / cpr;
        const int c = (int)(gg - row * cpr);
        const float* p = in + gg * 8;
        f32x4 v0 = *(const f32x4*)p;
        f32x4 v1 = *(const f32x4*)(p + 4);
        bf16x8 o;
        o[0] = (short)f32_to_bf16(v0[0]); o[1] = (short)f32_to_bf16(v0[1]);
        o[2] = (short)f32_to_bf16(v0[2]); o[3] = (short)f32_to_bf16(v0[3]);
        o[4] = (short)f32_to_bf16(v1[0]); o[5] = (short)f32_to_bf16(v1[1]);
        o[6] = (short)f32_to_bf16(v1[2]); o[7] = (short)f32_to_bf16(v1[3]);
        const int cdst = (c & ~7) | ((c & 7) ^ ((int)row & 7));
        *(bf16x8*)(out + (row * (long)cpr + cdst) * 8) = o;
    }
}

__device__ __forceinline__ void gload_lds16(const unsigned short* g, unsigned short* l) {
    __builtin_amdgcn_global_load_lds(
        (const __attribute__((address_space(1))) void*)g,
        (__attribute__((address_space(3))) void*)l, 16, 0, 0);
}

// Stage one 128x64 bf16 half-tile (16 KB): 2 global_load_lds x16 per thread.
// Source is PRE-SWIZZLED, so global read AND LDS dest are perfectly linear.
__device__ __forceinline__ void stage_half(const unsigned short* __restrict__ G,
                                           unsigned short* lds,
                                           int grow0, int gcol, int K, int tid) {
    const int wave = tid >> 6;
#pragma unroll
    for (int p = 0; p < 2; ++p) {
        const int s = tid + p * NTHREADS;            // 16B chunk 0..1023
        const int row = s >> 3;                      // 0..127
        const unsigned short* g = G + (size_t)(grow0 + row) * K + gcol + (s & 7) * 8;
        unsigned short* l = lds + (size_t)(wave * 64 + p * NTHREADS) * 8;
        gload_lds16(g, l);
    }
}

// R20: m201-exact 8-phase shape at R13 geometry. Phase =
//   [RD(this phase's operands) | STG | vmcnt?(P4/P8) | bar1 | lgkm0 |
//    sched_barrier | setprio(1) 16xMFMA setprio(0) | bar2 | sched_barrier]
// Reads are consumed by the SAME phase's MFMA (true data dependency -> the
// compiler cannot sink reads past their consumer; no R15-style race surface).
// Single a[4]/b[4] operand set (no ping-pong, -32 VGPR vs R13).
// Ring (symmetric, fully counted): buf1(t+1) staged P1-P2 (A1h0+B1h0@P1,
// A1h1+B1h1@P2), published at P4's bar1 with vmcnt draining exactly those 8
// (youngest 2 phases old -> ~zero wait); buf0(t+2) staged P5-P6, published at
// P8. Read-buffer != stage-buffer in every phase; every restage issues after
// the bar2 that follows the last reader's drained lgkm0 -> WAR airtight.
// (Ledger: R13 tail-read 242-244us/MfmaUtil 51; R14 head-read+ping-pong pins
// -35us; R15 32x32 loose RACED; R16/R17/R18 32x32 276-320us -> closed.)
__global__ __launch_bounds__(NTHREADS, 2)
void gemm8p(const unsigned short* __restrict__ Abf, const unsigned short* __restrict__ Bbf,
            const float* __restrict__ bias, float* __restrict__ out,
            int M, int N, int K) {
    // [buf][half][128 rows][64 k] bf16 (swizzled layout) — 128 KB total
    __shared__ unsigned short sA[2][2][128 * 64];
    __shared__ unsigned short sB[2][2][128 * 64];

    const int tid  = threadIdx.x;
    const int lane = tid & 63;
    const int wave = tid >> 6;
    const int wm = wave >> 2;          // 0..1 : A-half / wave's 128-row band
    const int wn = wave & 3;           // 0..3 : 64-col band (B-half = wn>>1)
    const int lrow = lane & 15;
    const int lkg  = lane >> 4;
    const int NT = K / BK;

    // Bijective XCD-chunk swizzle (T1); grid is (N/256, M/256).
    const int gx = gridDim.x;
    const int nwg = gx * gridDim.y;
    int lin = blockIdx.y * gx + blockIdx.x;
    if ((nwg & 7) == 0) lin = (lin & 7) * (nwg >> 3) + (lin >> 3);
    const int bm0 = (lin / gx) * BMN;
    const int bn0 = (lin % gx) * BMN;

    // Conflict-free fragment-read offsets: phys chunk = logical ^ (lrow&7).
    const int r7   = lrow & 7;
    const int lco0 = (lkg ^ r7) * 8;        // kk = 0
    const int lco1 = lco0 ^ 32;             // kk = 32 (XOR: carry-free)
    const int Aoff0 = lrow * 64 + lco0;
    const int Aoff1 = lrow * 64 + lco1;
    const int Boff0 = ((wn & 1) * 64 + lrow) * 64 + lco0;
    const int Boff1 = ((wn & 1) * 64 + lrow) * 64 + lco1;

    const unsigned short* Ab0 = &sA[0][wm][0];
    const unsigned short* Ab1 = &sA[1][wm][0];
    const unsigned short* Bb0 = &sB[0][wn >> 1][0];
    const unsigned short* Bb1 = &sB[1][wn >> 1][0];

    f32x4 acc[8][4];
    const f32x4 zero = {0.f, 0.f, 0.f, 0.f};
#pragma unroll
    for (int i = 0; i < 8; ++i)
#pragma unroll
        for (int j = 0; j < 4; ++j) acc[i][j] = zero;

    // Single operand set: reads are consumed by the same phase's MFMA.
    bf16x8 av[4], bv[4];

#define RD_A(base, q, off) { const unsigned short* _pa = (base); \
    _Pragma("unroll") for (int i = 0; i < 4; ++i) \
        av[i] = *(const bf16x8*)&_pa[((q) * 4 + i) * 1024 + (off)]; }
#define RD_B(base, off) { const unsigned short* _pb = (base); \
    _Pragma("unroll") for (int j = 0; j < 4; ++j) \
        bv[j] = *(const bf16x8*)&_pb[j * 1024 + (off)]; }

#define PH(q, RDS, STG, VMW) \
    RDS \
    STG \
    VMW \
    __builtin_amdgcn_s_barrier(); \
    asm volatile("s_waitcnt lgkmcnt(0)"); \
    __builtin_amdgcn_sched_barrier(0); \
    __builtin_amdgcn_s_setprio(1); \
    _Pragma("unroll") for (int i = 0; i < 4; ++i) \
    _Pragma("unroll") for (int j = 0; j < 4; ++j) \
        acc[(q) * 4 + i][j] = __builtin_amdgcn_mfma_f32_16x16x32_bf16(av[i], bv[j], acc[(q) * 4 + i][j], 0, 0, 0); \
    __builtin_amdgcn_s_setprio(0); \
    __builtin_amdgcn_s_barrier(); \
    __builtin_amdgcn_sched_barrier(0);

    // ---- prologue: buf0 <- tile0 (4 halves, 8 loads); full drain; publish.
    stage_half(Abf, &sA[0][0][0], bm0,       0, K, tid);
    stage_half(Abf, &sA[0][1][0], bm0 + 128, 0, K, tid);
    stage_half(Bbf, &sB[0][0][0], bn0,       0, K, tid);
    stage_half(Bbf, &sB[0][1][0], bn0 + 128, 0, K, tid);
    asm volatile("s_waitcnt vmcnt(0)");
    __builtin_amdgcn_s_barrier();
    __builtin_amdgcn_sched_barrier(0);

    // ---- main loop: 2 K-tiles per iteration (buf0 = t, buf1 = t+1).
    // vmcnt at publishes counts exactly the published buffer's 8 loads:
    //   P4: outstanding = P1(4)+P2(4) = 8 -> vmcnt(0), youngest 2 phases old.
    //   P8: outstanding = P5(4)+P6(4) = 8 -> vmcnt(0), youngest 2 phases old.
    // Overwrite audit: buf0 reads end P4 (drained at P4's lgkm0, before P4's
    // bar2); buf0 restage issues P5 (after P4's bar2). buf1 reads end P8;
    // buf1 restage issues next-P1 (after P8's bar2). Airtight.
    for (int t = 0; t < NT; t += 2) {
        int u2 = t + 2; if (u2 >= NT) u2 -= NT;   // wrap stage = harmless dummy
        const int k1 = (t + 1) * BK, k2 = u2 * BK;

        // P1: buf0 q0 kk0; stage buf1 A-h0 + B-h0 (t+1)
        PH(0, RD_A(Ab0, 0, Aoff0) RD_B(Bb0, Boff0),
           stage_half(Abf, &sA[1][0][0], bm0, k1, K, tid);
           stage_half(Bbf, &sB[1][0][0], bn0, k1, K, tid);, )

        // P2: buf0 q1 kk0; stage buf1 A-h1 + B-h1 (t+1)
        PH(1, RD_A(Ab0, 1, Aoff0),
           stage_half(Abf, &sA[1][1][0], bm0 + 128, k1, K, tid);
           stage_half(Bbf, &sB[1][1][0], bn0 + 128, k1, K, tid);, )

        // P3: buf0 q0 kk32
        PH(0, RD_A(Ab0, 0, Aoff1) RD_B(Bb0, Boff1), , )

        // P4: buf0 q1 kk32; drain P1/P2's 8 loads -> publish buf1(t+1)
        PH(1, RD_A(Ab0, 1, Aoff1), ,
           asm volatile("s_waitcnt vmcnt(0)");)

        // P5: buf1 q0 kk0; stage buf0 A-h0 + B-h0 (t+2)
        PH(0, RD_A(Ab1, 0, Aoff0) RD_B(Bb1, Boff0),
           stage_half(Abf, &sA[0][0][0], bm0, k2, K, tid);
           stage_half(Bbf, &sB[0][0][0], bn0, k2, K, tid);, )

        // P6: buf1 q1 kk0; stage buf0 A-h1 + B-h1 (t+2)
        PH(1, RD_A(Ab1, 1, Aoff0),
           stage_half(Abf, &sA[0][1][0], bm0 + 128, k2, K, tid);
           stage_half(Bbf, &sB[0][1][0], bn0 + 128, k2, K, tid);, )

        // P7: buf1 q0 kk32
        PH(0, RD_A(Ab1, 0, Aoff1) RD_B(Bb1, Boff1), , )

        // P8: buf1 q1 kk32; drain P5/P6's 8 loads -> publish buf0(t+2)
        PH(1, RD_A(Ab1, 1, Aoff1), ,
           asm volatile("s_waitcnt vmcnt(0)");)
    }

    asm volatile("s_waitcnt vmcnt(0) lgkmcnt(0)" ::: "memory");  // drain

    // ---- epilogue: + bias, final mantissa round, store fp32.
    // C/D layout (verified m89/m91): row = lkg*4 + reg, col = lrow.
#pragma unroll
    for (int ia = 0; ia < 8; ++ia) {
        const int row = bm0 + wm * 128 + ia * 16 + lkg * 4;
#pragma unroll
        for (int j = 0; j < 4; ++j) {
            const int col = bn0 + wn * 64 + j * 16 + lrow;
            const float bv = bias[col];
#pragma unroll
            for (int r = 0; r < 4; ++r)
                out[(size_t)(row + r) * N + col] = round_m10(acc[ia][j][r] + bv);
        }
    }
#undef RD_A
#undef RD_B
#undef PH
}

// Fallback: fused fp32->bf16 128^2 kernel (only for shapes the main path rejects).
__global__ __launch_bounds__(256)
void gemm_fallback(const float* __restrict__ A, const float* __restrict__ B,
                   const float* __restrict__ bias, float* __restrict__ out,
                   int M, int N, int K) {
    __shared__ unsigned short lds_a[128 * 64];
    __shared__ unsigned short lds_b[128 * 64];
    const int tid = threadIdx.x, lane = tid & 63, wave = tid >> 6;
    const int wm = wave >> 1, wn = wave & 1;
    const int bm0 = blockIdx.y * 128, bn0 = blockIdx.x * 128;
    const int lrow = lane & 15, lkg = lane >> 4;
    f32x4 acc[4][4];
    const f32x4 zero = {0.f, 0.f, 0.f, 0.f};
#pragma unroll
    for (int i = 0; i < 4; ++i)
#pragma unroll
        for (int j = 0; j < 4; ++j) acc[i][j] = zero;
    for (int kb = 0; kb < K / 64; ++kb) {
        const int kt = kb * 64;
        const int r0 = tid >> 4, c0 = (tid & 15) << 2;
#pragma unroll
        for (int p = 0; p < 8; ++p) {
            const int r = p * 16 + r0;
            f32x4 va = *(const f32x4*)(A + (size_t)(bm0 + r) * K + kt + c0);
            f32x4 vb = *(const f32x4*)(B + (size_t)(bn0 + r) * K + kt + c0);
            ushort4 ua, ub;
            ua.x = f32_to_bf16(va[0]); ua.y = f32_to_bf16(va[1]);
            ua.z = f32_to_bf16(va[2]); ua.w = f32_to_bf16(va[3]);
            ub.x = f32_to_bf16(vb[0]); ub.y = f32_to_bf16(vb[1]);
            ub.z = f32_to_bf16(vb[2]); ub.w = f32_to_bf16(vb[3]);
            *(ushort4*)(&lds_a[r * 64 + c0]) = ua;
            *(ushort4*)(&lds_b[r * 64 + c0]) = ub;
        }
        __syncthreads();
#pragma unroll
        for (int kk = 0; kk < 64; kk += 32) {
            bf16x8 af[4], bfr[4];
#pragma unroll
            for (int i = 0; i < 4; ++i)
                af[i] = *(const bf16x8*)(&lds_a[(wm * 64 + i * 16 + lrow) * 64 + kk + lkg * 8]);
#pragma unroll
            for (int j = 0; j < 4; ++j)
                bfr[j] = *(const bf16x8*)(&lds_b[(wn * 64 + j * 16 + lrow) * 64 + kk + lkg * 8]);
#pragma unroll
            for (int i = 0; i < 4; ++i)
#pragma unroll
                for (int j = 0; j < 4; ++j)
                    acc[i][j] = __builtin_amdgcn_mfma_f32_16x16x32_bf16(af[i], bfr[j], acc[i][j], 0, 0, 0);
        }
        __syncthreads();
    }
#pragma unroll
    for (int i = 0; i < 4; ++i) {
        const int row0 = bm0 + wm * 64 + i * 16 + lkg * 4;
#pragma unroll
        for (int j = 0; j < 4; ++j) {
            const int col = bn0 + wn * 64 + j * 16 + lrow;
            const float bv = bias[col];
#pragma unroll
            for (int r = 0; r < 4; ++r)
                out[(size_t)(row0 + r) * N + col] = round_m10(acc[i][j][r] + bv);
        }
    }
}

extern "C" void kernel_launch(void* const* d_in, const int* in_sizes, int n_in,
                              void* d_out, int out_size, void* d_ws, size_t ws_size,
                              hipStream_t stream) {
    const float* x    = (const float*)d_in[0];   // [M, K]
    const float* w    = (const float*)d_in[1];   // [N, K]
    const float* bias = (const float*)d_in[2];   // [N]
    float* out = (float*)d_out;                  // [M, N]

    const int N = in_sizes[2];
    const int K = in_sizes[1] / N;
    const int M = in_sizes[0] / K;

    const size_t nx = (size_t)M * K;
    const size_t nw = (size_t)N * K;
    const size_t need = (nx + nw) * sizeof(unsigned short);
    const int NT = K / BK;

    if (ws_size >= need && (M % BMN) == 0 && (N % BMN) == 0 && (K % BK) == 0 &&
        NT >= 4 && (NT % 2) == 0) {
        unsigned short* xb = (unsigned short*)d_ws;
        unsigned short* wb = xb + nx;
        const int cpr = K / 8;
        convert2_f32_bf16_swz<<<2048, 256, 0, stream>>>(
            x, xb, w, wb, (long)(nx / 8), (long)((nx + nw) / 8), cpr);
        dim3 grid(N / BMN, M / BMN);
        gemm8p<<<grid, NTHREADS, 0, stream>>>(xb, wb, bias, out, M, N, K);
    } else {
        dim3 grid(N / 128, M / 128);
        gemm_fallback<<<grid, 256, 0, stream>>>(x, w, bias, out, M, N, K);
    }
}

// Round 8
// 293.674 us; speedup vs baseline: 1.0373x; 1.0373x over previous
//
#include <hip/hip_runtime.h>
#include <stdint.h>
#include <stddef.h>

typedef __attribute__((ext_vector_type(4))) float f32x4;
typedef __attribute__((ext_vector_type(8))) short bf16x8;

#define BMN 256      // block tile M = N
#define BK  64       // K per K-tile
#define NTHREADS 512

// Round-to-nearest-even fp32 mantissa to 10 bits (shift = 23-10 = 13).
__device__ __forceinline__ float round_m10(float x) {
    int b = __float_as_int(x);
    int rb = ((b >> 13) & 1) + 0x0FFF;
    b = (b + rb) & (int)0xFFFFE000;
    return __int_as_float(b);
}

__device__ __forceinline__ unsigned short f32_to_bf16(float x) {
    unsigned int u = __float_as_uint(x);
    u += 0x7FFFu + ((u >> 16) & 1u);
    return (unsigned short)(u >> 16);
}

// fp32 -> bf16 with the 3-bit bank swizzle BAKED IN: the 16B chunk at logical
// (row, c) is stored at (row, (c & ~7) | ((c&7) ^ (row&7))). Permutation acts
// within each 128B row-window; all tile offsets are 128B-aligned, so LDS
// staging reads LINEARLY and inherits the swizzle (rule #21).
// FUSED single launch for both tensors (x then w) — verified R19.
__global__ void convert2_f32_bf16_swz(const float* __restrict__ inx,
                                      unsigned short* __restrict__ outx,
                                      const float* __restrict__ inw,
                                      unsigned short* __restrict__ outw,
                                      long nx8, long ntot, int cpr) {
    long g = (long)blockIdx.x * blockDim.x + threadIdx.x;
    const long stride = (long)gridDim.x * blockDim.x;
    for (; g < ntot; g += stride) {
        const float* in;
        unsigned short* out;
        long gg;
        if (g < nx8) { in = inx; out = outx; gg = g; }
        else         { in = inw; out = outw; gg = g - nx8; }
        const long row = gg / cpr;
        const int c = (int)(gg - row * cpr);
        const float* p = in + gg * 8;
        f32x4 v0 = *(const f32x4*)p;
        f32x4 v1 = *(const f32x4*)(p + 4);
        bf16x8 o;
        o[0] = (short)f32_to_bf16(v0[0]); o[1] = (short)f32_to_bf16(v0[1]);
        o[2] = (short)f32_to_bf16(v0[2]); o[3] = (short)f32_to_bf16(v0[3]);
        o[4] = (short)f32_to_bf16(v1[0]); o[5] = (short)f32_to_bf16(v1[1]);
        o[6] = (short)f32_to_bf16(v1[2]); o[7] = (short)f32_to_bf16(v1[3]);
        const int cdst = (c & ~7) | ((c & 7) ^ ((int)row & 7));
        *(bf16x8*)(out + (row * (long)cpr + cdst) * 8) = o;
    }
}

__device__ __forceinline__ void gload_lds16(const unsigned short* g, unsigned short* l) {
    __builtin_amdgcn_global_load_lds(
        (const __attribute__((address_space(1))) void*)g,
        (__attribute__((address_space(3))) void*)l, 16, 0, 0);
}

// Stage one 128x64 bf16 half-tile (16 KB): 2 global_load_lds x16 per thread.
// Source is PRE-SWIZZLED, so global read AND LDS dest are perfectly linear.
__device__ __forceinline__ void stage_half(const unsigned short* __restrict__ G,
                                           unsigned short* lds,
                                           int grow0, int gcol, int K, int tid) {
    const int wave = tid >> 6;
#pragma unroll
    for (int p = 0; p < 2; ++p) {
        const int s = tid + p * NTHREADS;            // 16B chunk 0..1023
        const int row = s >> 3;                      // 0..127
        const unsigned short* g = G + (size_t)(grow0 + row) * K + gcol + (s & 7) * 8;
        unsigned short* l = lds + (size_t)(wave * 64 + p * NTHREADS) * 8;
        gload_lds16(g, l);
    }
}

// R21: R13's single-barrier TAIL-READ shape, deepened to 2-phases-ahead with
// COUNTED lgkm waits. Tail of phase k reads operands for phase k+2; the head
// wait lgkmcnt(count of tail k-1) targets reads issued a full phase + MFMA
// cluster earlier -> residual LDS drain ~0. Same 4 operand sets as R13 (each
// set is rewritten in the region its consumer MFMA just ran). Stage ring
// re-timed for the earlier buffer-crossing reads (at tails P3/P7):
//   STG_4: A0h0+B0h0(t+2), STG_5: A0h1+B0h1(t+2), STG_8: A1+B1 (t+3, 8 loads)
//   VM_3: vmcnt(0) drains STG_8prev's 8 (>=3 regions old) -> publish buf1(t+1)
//   VM_7: vmcnt(0) drains STG_4+5's 8 (>=2 regions old) -> publish buf0(t+2)
// lgkm counts alternate 4/8 (tails alternate 8,4,8,4...; in-order LDS
// completion makes prefix counts exact). Restage-vs-last-read-issue margin
// >= 2 regions everywhere (>= R13's verified margin).
// (Ledger: R13/R19 tail-read 242us MfmaUtil 51.6; R14 head-read -35us; R20
// m201-shape 310us; R16/R17 2-barrier 37-38% MfmaUtil; 32x32 line closed.)
__global__ __launch_bounds__(NTHREADS, 2)
void gemm8p(const unsigned short* __restrict__ Abf, const unsigned short* __restrict__ Bbf,
            const float* __restrict__ bias, float* __restrict__ out,
            int M, int N, int K) {
    // [buf][half][128 rows][64 k] bf16 (swizzled layout) — 128 KB total
    __shared__ unsigned short sA[2][2][128 * 64];
    __shared__ unsigned short sB[2][2][128 * 64];

    const int tid  = threadIdx.x;
    const int lane = tid & 63;
    const int wave = tid >> 6;
    const int wm = wave >> 2;          // 0..1 : A-half / wave's 128-row band
    const int wn = wave & 3;           // 0..3 : 64-col band (B-half = wn>>1)
    const int lrow = lane & 15;
    const int lkg  = lane >> 4;
    const int NT = K / BK;

    // Bijective XCD-chunk swizzle (T1); grid is (N/256, M/256).
    const int gx = gridDim.x;
    const int nwg = gx * gridDim.y;
    int lin = blockIdx.y * gx + blockIdx.x;
    if ((nwg & 7) == 0) lin = (lin & 7) * (nwg >> 3) + (lin >> 3);
    const int bm0 = (lin / gx) * BMN;
    const int bn0 = (lin % gx) * BMN;

    // Conflict-free fragment-read offsets: phys chunk = logical ^ (lrow&7).
    const int r7   = lrow & 7;
    const int lco0 = (lkg ^ r7) * 8;        // kk = 0
    const int lco1 = lco0 ^ 32;             // kk = 32 (XOR: carry-free)
    const int Aoff0 = lrow * 64 + lco0;
    const int Aoff1 = lrow * 64 + lco1;
    const int Boff0 = ((wn & 1) * 64 + lrow) * 64 + lco0;
    const int Boff1 = ((wn & 1) * 64 + lrow) * 64 + lco1;

    const unsigned short* Ab0 = &sA[0][wm][0];
    const unsigned short* Ab1 = &sA[1][wm][0];
    const unsigned short* Bb0 = &sB[0][wn >> 1][0];
    const unsigned short* Bb1 = &sB[1][wn >> 1][0];

    f32x4 acc[8][4];
    const f32x4 zero = {0.f, 0.f, 0.f, 0.f};
#pragma unroll
    for (int i = 0; i < 8; ++i)
#pragma unroll
        for (int j = 0; j < 4; ++j) acc[i][j] = zero;

    // Ping-pong operand sets (R13-identical): A per phase; B per 2 phases.
    bf16x8 aS0[4], aS1[4], bS0[4], bS1[4];

#define RD_A(dst, base, q, off) { const unsigned short* _pa = (base); \
    _Pragma("unroll") for (int i = 0; i < 4; ++i) \
        dst[i] = *(const bf16x8*)&_pa[((q) * 4 + i) * 1024 + (off)]; }
#define RD_B(dst, base, off) { const unsigned short* _pb = (base); \
    _Pragma("unroll") for (int j = 0; j < 4; ++j) \
        dst[j] = *(const bf16x8*)&_pb[j * 1024 + (off)]; }

// Single barrier per phase; COUNTED lgkm wait (LG = #ds_reads issued in the
// PREVIOUS phase's tail — the only reads younger than this phase's operands).
#define PH(q, LG, aU, bU, RDS, STG, VMW) \
    STG \
    VMW \
    __builtin_amdgcn_s_barrier(); \
    asm volatile("s_waitcnt lgkmcnt(" LG ")"); \
    __builtin_amdgcn_sched_barrier(0); \
    __builtin_amdgcn_s_setprio(1); \
    _Pragma("unroll") for (int i = 0; i < 4; ++i) \
    _Pragma("unroll") for (int j = 0; j < 4; ++j) \
        acc[(q) * 4 + i][j] = __builtin_amdgcn_mfma_f32_16x16x32_bf16(aU[i], bU[j], acc[(q) * 4 + i][j], 0, 0, 0); \
    __builtin_amdgcn_s_setprio(0); \
    RDS

    // ---- prologue: buf0 (tile0) + buf1 (tile1), 16 loads; drain tile0 only.
    stage_half(Abf, &sA[0][0][0], bm0,       0,  K, tid);
    stage_half(Abf, &sA[0][1][0], bm0 + 128, 0,  K, tid);
    stage_half(Bbf, &sB[0][0][0], bn0,       0,  K, tid);
    stage_half(Bbf, &sB[0][1][0], bn0 + 128, 0,  K, tid);
    stage_half(Abf, &sA[1][0][0], bm0,       BK, K, tid);
    stage_half(Abf, &sA[1][1][0], bm0 + 128, BK, K, tid);
    stage_half(Bbf, &sB[1][0][0], bn0,       BK, K, tid);
    stage_half(Bbf, &sB[1][1][0], bn0 + 128, BK, K, tid);
    asm volatile("s_waitcnt vmcnt(8)");      // buf0's 8 landed; buf1's 8 in flight
    __builtin_amdgcn_s_barrier();
    // Steady-state image: M1 ops (8 reads) then M2 ops (4 reads) outstanding.
    RD_A(aS0, Ab0, 0, Aoff0)
    RD_B(bS0, Bb0, Boff0)
    RD_A(aS1, Ab0, 1, Aoff0)

    // ---- main loop: 2 K-tiles per iteration (buf0 = t, buf1 = t+1).
    // Tail schedule (2-ahead): tail_k holds ops for MFMA_{k+2}.
    //   tails: P1=8(M3) P2=4(M4) P3=8(M5) P4=4(M6) P5=8(M7) P6=4(M8)
    //          P7=8(M1') P8=4(M2')   -> LG at head: 4,8,4,8,4,8,4,8.
    // Publish/restage audit in header comment.
    for (int t = 0; t < NT; t += 2) {
        int u2 = t + 2; if (u2 >= NT) u2 -= NT;   // wrap stages = harmless dummies
        int u3 = t + 3; if (u3 >= NT) u3 -= NT;
        const int k2 = u2 * BK, k3 = u3 * BK;

        // P1: MFMA buf0 q0 kk0; tail: M3 ops (Ab0 q0 kk32 + Bb0 kk32)
        PH(0, "4", aS0, bS0,
           RD_A(aS0, Ab0, 0, Aoff1) RD_B(bS1, Bb0, Boff1), , )

        // P2: q1 kk0; tail: M4 ops (Ab0 q1 kk32)
        PH(1, "8", aS1, bS0,
           RD_A(aS1, Ab0, 1, Aoff1), , )

        // P3: q0 kk32; vmcnt(0) drains STG_8prev's 8 -> publish buf1(t+1);
        //     tail: M5 ops (Ab1 q0 kk0 + Bb1 kk0)
        PH(0, "4", aS0, bS1,
           RD_A(aS0, Ab1, 0, Aoff0) RD_B(bS0, Bb1, Boff0),
           , asm volatile("s_waitcnt vmcnt(0)");)

        // P4: q1 kk32; stage A0h0+B0h0 (t+2); tail: M6 ops (Ab1 q1 kk0)
        PH(1, "8", aS1, bS1,
           RD_A(aS1, Ab1, 1, Aoff0),
           stage_half(Abf, &sA[0][0][0], bm0, k2, K, tid);
           stage_half(Bbf, &sB[0][0][0], bn0, k2, K, tid);, )

        // P5: buf1 q0 kk0; stage A0h1+B0h1 (t+2); tail: M7 ops (Ab1 kk32 + Bb1 kk32)
        PH(0, "4", aS0, bS0,
           RD_A(aS0, Ab1, 0, Aoff1) RD_B(bS1, Bb1, Boff1),
           stage_half(Abf, &sA[0][1][0], bm0 + 128, k2, K, tid);
           stage_half(Bbf, &sB[0][1][0], bn0 + 128, k2, K, tid);, )

        // P6: q1 kk0; tail: M8 ops (Ab1 q1 kk32)
        PH(1, "8", aS1, bS0,
           RD_A(aS1, Ab1, 1, Aoff1), , )

        // P7: q0 kk32; vmcnt(0) drains STG_4+5's 8 -> publish buf0(t+2);
        //     tail: M1' ops (Ab0 q0 kk0 + Bb0 kk0)
        PH(0, "4", aS0, bS1,
           RD_A(aS0, Ab0, 0, Aoff0) RD_B(bS0, Bb0, Boff0),
           , asm volatile("s_waitcnt vmcnt(0)");)

        // P8: q1 kk32; stage buf1 (t+3, 8 loads); tail: M2' ops (Ab0 q1 kk0)
        PH(1, "8", aS1, bS1,
           RD_A(aS1, Ab0, 1, Aoff0),
           stage_half(Abf, &sA[1][0][0], bm0, k3, K, tid);
           stage_half(Abf, &sA[1][1][0], bm0 + 128, k3, K, tid);
           stage_half(Bbf, &sB[1][0][0], bn0, k3, K, tid);
           stage_half(Bbf, &sB[1][1][0], bn0 + 128, k3, K, tid);, )
    }

    asm volatile("s_waitcnt vmcnt(0) lgkmcnt(0)" ::: "memory");  // drain

    // ---- epilogue: + bias, final mantissa round, store fp32.
    // C/D layout (verified m89/m91): row = lkg*4 + reg, col = lrow.
#pragma unroll
    for (int ia = 0; ia < 8; ++ia) {
        const int row = bm0 + wm * 128 + ia * 16 + lkg * 4;
#pragma unroll
        for (int j = 0; j < 4; ++j) {
            const int col = bn0 + wn * 64 + j * 16 + lrow;
            const float bv = bias[col];
#pragma unroll
            for (int r = 0; r < 4; ++r)
                out[(size_t)(row + r) * N + col] = round_m10(acc[ia][j][r] + bv);
        }
    }
#undef RD_A
#undef RD_B
#undef PH
}

// Fallback: fused fp32->bf16 128^2 kernel (only for shapes the main path rejects).
__global__ __launch_bounds__(256)
void gemm_fallback(const float* __restrict__ A, const float* __restrict__ B,
                   const float* __restrict__ bias, float* __restrict__ out,
                   int M, int N, int K) {
    __shared__ unsigned short lds_a[128 * 64];
    __shared__ unsigned short lds_b[128 * 64];
    const int tid = threadIdx.x, lane = tid & 63, wave = tid >> 6;
    const int wm = wave >> 1, wn = wave & 1;
    const int bm0 = blockIdx.y * 128, bn0 = blockIdx.x * 128;
    const int lrow = lane & 15, lkg = lane >> 4;
    f32x4 acc[4][4];
    const f32x4 zero = {0.f, 0.f, 0.f, 0.f};
#pragma unroll
    for (int i = 0; i < 4; ++i)
#pragma unroll
        for (int j = 0; j < 4; ++j) acc[i][j] = zero;
    for (int kb = 0; kb < K / 64; ++kb) {
        const int kt = kb * 64;
        const int r0 = tid >> 4, c0 = (tid & 15) << 2;
#pragma unroll
        for (int p = 0; p < 8; ++p) {
            const int r = p * 16 + r0;
            f32x4 va = *(const f32x4*)(A + (size_t)(bm0 + r) * K + kt + c0);
            f32x4 vb = *(const f32x4*)(B + (size_t)(bn0 + r) * K + kt + c0);
            ushort4 ua, ub;
            ua.x = f32_to_bf16(va[0]); ua.y = f32_to_bf16(va[1]);
            ua.z = f32_to_bf16(va[2]); ua.w = f32_to_bf16(va[3]);
            ub.x = f32_to_bf16(vb[0]); ub.y = f32_to_bf16(vb[1]);
            ub.z = f32_to_bf16(vb[2]); ub.w = f32_to_bf16(vb[3]);
            *(ushort4*)(&lds_a[r * 64 + c0]) = ua;
            *(ushort4*)(&lds_b[r * 64 + c0]) = ub;
        }
        __syncthreads();
#pragma unroll
        for (int kk = 0; kk < 64; kk += 32) {
            bf16x8 af[4], bfr[4];
#pragma unroll
            for (int i = 0; i < 4; ++i)
                af[i] = *(const bf16x8*)(&lds_a[(wm * 64 + i * 16 + lrow) * 64 + kk + lkg * 8]);
#pragma unroll
            for (int j = 0; j < 4; ++j)
                bfr[j] = *(const bf16x8*)(&lds_b[(wn * 64 + j * 16 + lrow) * 64 + kk + lkg * 8]);
#pragma unroll
            for (int i = 0; i < 4; ++i)
#pragma unroll
                for (int j = 0; j < 4; ++j)
                    acc[i][j] = __builtin_amdgcn_mfma_f32_16x16x32_bf16(af[i], bfr[j], acc[i][j], 0, 0, 0);
        }
        __syncthreads();
    }
#pragma unroll
    for (int i = 0; i < 4; ++i) {
        const int row0 = bm0 + wm * 64 + i * 16 + lkg * 4;
#pragma unroll
        for (int j = 0; j < 4; ++j) {
            const int col = bn0 + wn * 64 + j * 16 + lrow;
            const float bv = bias[col];
#pragma unroll
            for (int r = 0; r < 4; ++r)
                out[(size_t)(row0 + r) * N + col] = round_m10(acc[i][j][r] + bv);
        }
    }
}

extern "C" void kernel_launch(void* const* d_in, const int* in_sizes, int n_in,
                              void* d_out, int out_size, void* d_ws, size_t ws_size,
                              hipStream_t stream) {
    const float* x    = (const float*)d_in[0];   // [M, K]
    const float* w    = (const float*)d_in[1];   // [N, K]
    const float* bias = (const float*)d_in[2];   // [N]
    float* out = (float*)d_out;                  // [M, N]

    const int N = in_sizes[2];
    const int K = in_sizes[1] / N;
    const int M = in_sizes[0] / K;

    const size_t nx = (size_t)M * K;
    const size_t nw = (size_t)N * K;
    const size_t need = (nx + nw) * sizeof(unsigned short);
    const int NT = K / BK;

    if (ws_size >= need && (M % BMN) == 0 && (N % BMN) == 0 && (K % BK) == 0 &&
        NT >= 4 && (NT % 2) == 0) {
        unsigned short* xb = (unsigned short*)d_ws;
        unsigned short* wb = xb + nx;
        const int cpr = K / 8;
        convert2_f32_bf16_swz<<<2048, 256, 0, stream>>>(
            x, xb, w, wb, (long)(nx / 8), (long)((nx + nw) / 8), cpr);
        dim3 grid(N / BMN, M / BMN);
        gemm8p<<<grid, NTHREADS, 0, stream>>>(xb, wb, bias, out, M, N, K);
    } else {
        dim3 grid(N / 128, M / 128);
        gemm_fallback<<<grid, 256, 0, stream>>>(x, w, bias, out, M, N, K);
    }
}